// Round 4
// baseline (291.413 us; speedup 1.0000x reference)
//
#include <hip/hip_runtime.h>
#include <cstdint>

#define DEV __device__ __forceinline__

typedef float f32x4 __attribute__((ext_vector_type(4)));
typedef short s16x8 __attribute__((ext_vector_type(8)));

DEV unsigned short f2bf(float f){
    unsigned u = __builtin_bit_cast(unsigned, f);
    u = u + 0x7fffu + ((u >> 16) & 1u);   // RNE
    return (unsigned short)(u >> 16);
}
DEV float bf2f(unsigned short h){
    unsigned u = ((unsigned)h) << 16;
    return __builtin_bit_cast(float, u);
}

typedef const void __attribute__((address_space(1)))* gcp;
typedef void __attribute__((address_space(3)))* lp;
DEV void gload_lds16(const void* g, void* l){
    // async global->LDS, 16B per lane; LDS dest = wave-uniform base + lane*16
    __builtin_amdgcn_global_load_lds((gcp)g, (lp)l, 16, 0, 0);
}

#define SCALE_QK 0.04419417382415922f   // 1/sqrt(512)

// ---------------------------------------------------------------------------
// Conv (grid 3073):
//   blocks 0..1023  : Q -> bf16, K -> bf16 (RAW: dragon weight factored out
//                     of the dot product, applied in gemm_qk epilogue)
//   blocks 1024..3071: V -> Vt (bf16 [b][d][s]) + vmean atomics
//   block 3072      : dragon pattern + blend (runs concurrently; nothing in
//                     this dispatch consumes its outputs)
// ---------------------------------------------------------------------------
__global__ __launch_bounds__(256) void k_conv(
    const float* __restrict__ Q, const float* __restrict__ K,
    const float* __restrict__ V,
    const float* __restrict__ scale, const float* __restrict__ bias,
    const float* __restrict__ w1, const float* __restrict__ b1,
    const float* __restrict__ w2, const float* __restrict__ b2,
    unsigned short* __restrict__ Qb, unsigned short* __restrict__ Kb,
    unsigned short* __restrict__ Vt, float* __restrict__ vmean,
    float* __restrict__ dragon_wq, float* __restrict__ blend_out)
{
    __shared__ float sh[8200];
    int tid = threadIdx.x;
    int bx  = blockIdx.x;

    if (bx < 1024){
        // ---- Q,K -> bf16 streaming (192 MB traffic) ----
        const long long total4 = (long long)8*2048*512/4;   // 2097152
        long long stride = 1024LL*256;
        for (long long i = (long long)bx*256 + tid; i < total4; i += stride){
            long long base = i*4;
            const float4 q = *(const float4*)(Q + base);
            const float4 k = *(const float4*)(K + base);
            ushort4 qo, ko;
            qo.x = f2bf(q.x); qo.y = f2bf(q.y); qo.z = f2bf(q.z); qo.w = f2bf(q.w);
            ko.x = f2bf(k.x); ko.y = f2bf(k.y); ko.z = f2bf(k.z); ko.w = f2bf(k.w);
            *(ushort4*)(Qb + base) = qo;
            *(ushort4*)(Kb + base) = ko;
        }
        return;
    }

    if (bx < 3072){
        // ---- V transpose + vmean atomics ----
        int t = bx - 1024;                    // 0..2047 = 32 stile x 8 dtile x 8 b
        int stile = t & 31, dtile = (t >> 5) & 7, b = t >> 8;
        int s0 = stile*64, d0 = dtile*64;
        float (*tile)[66] = (float(*)[66])sh;  // 64x66 = 4224 floats
        float* red = sh + 4224;                // 256 floats
        int tx = tid & 63, ty = tid >> 6;
        const float* src = V + ((long long)b*2048 + s0)*512 + d0;
        #pragma unroll
        for (int r = 0; r < 16; ++r){
            int row = r*4 + ty;
            tile[row][tx] = src[(long long)row*512 + tx];
        }
        __syncthreads();
        unsigned short* dst = Vt + ((long long)b*512 + d0)*2048 + s0;
        #pragma unroll
        for (int r = 0; r < 16; ++r){
            int drow = r*4 + ty;
            dst[(long long)drow*2048 + tx] = f2bf(tile[tx][drow]);
        }
        int dcol = tid & 63, sp = tid >> 6;
        float s = 0.f;
        #pragma unroll
        for (int ii = 0; ii < 16; ++ii) s += tile[sp*16 + ii][dcol];
        red[sp*64 + dcol] = s;
        __syncthreads();
        if (sp == 0){
            float tot = red[dcol] + red[64+dcol] + red[128+dcol] + red[192+dcol];
            atomicAdd(&vmean[b*512 + d0 + dcol], tot * (1.0f/2048.0f));
        }
        return;
    }

    // ---- dragon pattern + blend (1 block) ----
    // pattern[11] length 4095 = 2*2048-1 -> np.interp picks element 2i.
    float* A    = sh;             // 4095
    float* Bb   = sh + 4095;      // 4095
    float* red8 = sh + 8190;      // 8
    int lane = tid & 63, w = tid >> 6;
    if (tid == 0) A[0] = 0.5f;
    __syncthreads();
    float lo = 0.f, rden = 1.f;   // patterns[0] used raw (no normalize)
    int len = 1;
    const float third = 1.0f/3.0f;
    for (int it = 1; it < 12; ++it){
        int n = len, nl = 2*n + 1;
        // expand with carried normalization of A
        for (int i = tid; i < nl; i += 256){
            float v;
            if (i < n)       v = (A[i] - lo) * rden;
            else if (i == n) v = 0.5f;
            else             v = 1.0f - (A[2*n - i] - lo) * rden;
            Bb[i] = v;
        }
        __syncthreads();
        // conv [1/3,1/3,1/3] zero-pad 'same'; fused local min/max
        float mn = 3.4e38f, mx = -3.4e38f;
        for (int i = tid; i < nl; i += 256){
            float s = Bb[i];
            if (i > 0)    s += Bb[i-1];
            if (i < nl-1) s += Bb[i+1];
            s *= third;
            A[i] = s;
            mn = fminf(mn, s); mx = fmaxf(mx, s);
        }
        #pragma unroll
        for (int off = 32; off > 0; off >>= 1){
            mn = fminf(mn, __shfl_xor(mn, off, 64));
            mx = fmaxf(mx, __shfl_xor(mx, off, 64));
        }
        if (lane == 0){ red8[w] = mn; red8[4 + w] = mx; }
        __syncthreads();
        mn = fminf(fminf(red8[0], red8[1]), fminf(red8[2], red8[3]));
        mx = fmaxf(fmaxf(red8[4], red8[5]), fmaxf(red8[6], red8[7]));
        lo = mn; rden = 1.0f / (mx - mn + 1e-8f);
        len = nl;
        __syncthreads();
    }
    // dragon_wq[s] = softplus(normpat[2s]*scale[11]+bias[11]) * 1/sqrt(512)
    float sc = scale[11], bi = bias[11];
    for (int i = tid; i < 2048; i += 256){
        float x = (A[2*i] - lo) * rden * sc + bi;
        dragon_wq[i] = (fmaxf(x, 0.f) + log1pf(__expf(-fabsf(x)))) * SCALE_QK;
    }
    if (tid < 64){
        float h = fmaxf(w1[11*64 + tid] + b1[tid], 0.f);
        float c = h * w2[tid];
        for (int off = 32; off > 0; off >>= 1) c += __shfl_xor(c, off, 64);
        if (tid == 0) blend_out[0] = 1.f/(1.f + __expf(-(c + b2[0])));
    }
}

// ---------------------------------------------------------------------------
// GEMM 1: Sp[b,q,k] = bf16( exp( (Qb . Kb^T) * wq[k] ) )   (wq = w/sqrt(512))
// 128q x 256k tile, BK=64, 4 waves (2x2), 4x8 MFMA 16x16x32 per wave.
// 2x MFMA per barrier vs 128x128; LDS XOR-swizzled -> 0 bank conflicts.
// ---------------------------------------------------------------------------
__global__ __launch_bounds__(256) void k_gemm_qk(
    const unsigned short* __restrict__ Qb, const unsigned short* __restrict__ Kb,
    const float* __restrict__ dragon_wq, unsigned short* __restrict__ Sp)
{
    __shared__ unsigned short At[128*64];
    __shared__ unsigned short Bt[256*64];
    int tid = threadIdx.x;
    int lane = tid & 63, wave = tid >> 6;
    int wm = wave >> 1, wn = wave & 1;
    int ln = lane & 15, q4 = lane >> 4;
    int sx = ln & 7;
    int q0 = blockIdx.y*128, k0 = blockIdx.x*256, b = blockIdx.z;
    const unsigned short* Abase = Qb + ((long long)b*2048 + q0)*512;
    const unsigned short* Bbase = Kb + ((long long)b*2048 + k0)*512;

    f32x4 acc[4][8];
    #pragma unroll
    for (int i = 0; i < 4; ++i)
        #pragma unroll
        for (int j = 0; j < 8; ++j) acc[i][j] = (f32x4)0.0f;

    int cc = lane & 7, rg = lane >> 3;
    for (int kt = 0; kt < 8; ++kt){
        #pragma unroll
        for (int c = 0; c < 4; ++c){            // A: 16 chunks of 1KB
            int chunk = wave*4 + c;
            int row = chunk*8 + rg;
            int gc  = cc ^ (row & 7);
            gload_lds16(Abase + (long long)row*512 + kt*64 + gc*8, &At[chunk*512]);
        }
        #pragma unroll
        for (int c = 0; c < 8; ++c){            // B: 32 chunks of 1KB
            int chunk = wave*8 + c;
            int row = chunk*8 + rg;
            int gc  = cc ^ (row & 7);
            gload_lds16(Bbase + (long long)row*512 + kt*64 + gc*8, &Bt[chunk*512]);
        }
        __syncthreads();
        #pragma unroll
        for (int ks = 0; ks < 2; ++ks){
            int cs = ((ks*4 + q4) ^ sx) * 8;
            s16x8 af[4], bfr[8];
            #pragma unroll
            for (int i = 0; i < 4; ++i)
                af[i] = *(const s16x8*)&At[(wm*64 + i*16 + ln)*64 + cs];
            #pragma unroll
            for (int j = 0; j < 8; ++j)
                bfr[j] = *(const s16x8*)&Bt[(wn*128 + j*16 + ln)*64 + cs];
            #pragma unroll
            for (int i = 0; i < 4; ++i)
                #pragma unroll
                for (int j = 0; j < 8; ++j)
                    acc[i][j] = __builtin_amdgcn_mfma_f32_16x16x32_bf16(af[i], bfr[j], acc[i][j], 0, 0, 0);
        }
        __syncthreads();
    }
    float wq[8];
    #pragma unroll
    for (int j = 0; j < 8; ++j) wq[j] = dragon_wq[k0 + wn*128 + j*16 + ln];
    unsigned short* outp = Sp + (long long)b*2048*2048;
    #pragma unroll
    for (int i = 0; i < 4; ++i){
        #pragma unroll
        for (int j = 0; j < 8; ++j){
            #pragma unroll
            for (int r = 0; r < 4; ++r){
                int q = q0 + wm*64 + i*16 + q4*4 + r;   // C/D: row=(lane>>4)*4+reg
                int k = k0 + wn*128 + j*16 + ln;        //      col=lane&15
                outp[(long long)q*2048 + k] = f2bf(__expf(acc[i][j][r] * wq[j]));
            }
        }
    }
}

// ---------------------------------------------------------------------------
// GEMM 2: out[b,q,d] = blend * (Sp . V) / l[q] + (1-blend) * Vmean[d]
// l[q] = sum_k Sp[q,k] accumulated from the A-fragments (wn==0 waves only).
// 128x128 tile (512 blocks keeps >=2 co-resident blocks/CU for overlap).
// ---------------------------------------------------------------------------
__global__ __launch_bounds__(256) void k_gemm_pv(
    const unsigned short* __restrict__ Sp, const unsigned short* __restrict__ Vt,
    const float* __restrict__ vmean, const float* __restrict__ blendp,
    float* __restrict__ out)
{
    __shared__ unsigned short At[128*64];
    __shared__ unsigned short Bt[128*64];
    __shared__ float l_sh[128];
    int tid = threadIdx.x;
    int lane = tid & 63, wave = tid >> 6;
    int wm = wave >> 1, wn = wave & 1;
    int ln = lane & 15, q4 = lane >> 4;
    int sx = ln & 7;
    int q0 = blockIdx.y*128, d0 = blockIdx.x*128, b = blockIdx.z;
    const unsigned short* Abase = Sp + (long long)b*2048*2048 + (long long)q0*2048;
    const unsigned short* Bbase = Vt + ((long long)b*512 + d0)*2048;

    f32x4 acc[4][4];
    #pragma unroll
    for (int i = 0; i < 4; ++i)
        #pragma unroll
        for (int j = 0; j < 4; ++j) acc[i][j] = (f32x4)0.0f;
    float lsum[4] = {0.f, 0.f, 0.f, 0.f};

    int cc = lane & 7, rg = lane >> 3;
    for (int kt = 0; kt < 32; ++kt){
        #pragma unroll
        for (int c = 0; c < 4; ++c){
            int chunk = wave*4 + c;
            int row = chunk*8 + rg;
            int gc  = cc ^ (row & 7);
            gload_lds16(Abase + (long long)row*2048 + kt*64 + gc*8, &At[chunk*512]);
            gload_lds16(Bbase + (long long)row*2048 + kt*64 + gc*8, &Bt[chunk*512]);
        }
        __syncthreads();
        #pragma unroll
        for (int ks = 0; ks < 2; ++ks){
            int cs = ((ks*4 + q4) ^ sx) * 8;
            s16x8 af[4], bfr[4];
            #pragma unroll
            for (int i = 0; i < 4; ++i)
                af[i] = *(const s16x8*)&At[(wm*64 + i*16 + ln)*64 + cs];
            #pragma unroll
            for (int j = 0; j < 4; ++j)
                bfr[j] = *(const s16x8*)&Bt[(wn*64 + j*16 + ln)*64 + cs];
            if (wn == 0){
                #pragma unroll
                for (int i = 0; i < 4; ++i){
                    float s = 0.f;
                    #pragma unroll
                    for (int jj = 0; jj < 8; ++jj) s += bf2f((unsigned short)af[i][jj]);
                    lsum[i] += s;
                }
            }
            #pragma unroll
            for (int i = 0; i < 4; ++i)
                #pragma unroll
                for (int j = 0; j < 4; ++j)
                    acc[i][j] = __builtin_amdgcn_mfma_f32_16x16x32_bf16(af[i], bfr[j], acc[i][j], 0, 0, 0);
        }
        __syncthreads();
    }
    if (wn == 0){
        #pragma unroll
        for (int i = 0; i < 4; ++i){
            float v = lsum[i];
            v += __shfl_xor(v, 16, 64);
            v += __shfl_xor(v, 32, 64);
            if (lane < 16) l_sh[wm*64 + i*16 + lane] = v;
        }
    }
    __syncthreads();

    float blend = blendp[0];
    float ib = 1.0f - blend;
    float* obase = out + ((long long)b*2048 + q0)*512 + d0;
    float vm[4];
    #pragma unroll
    for (int j = 0; j < 4; ++j) vm[j] = vmean[b*512 + d0 + wn*64 + j*16 + ln];
    #pragma unroll
    for (int i = 0; i < 4; ++i){
        #pragma unroll
        for (int r = 0; r < 4; ++r){
            int ql = wm*64 + i*16 + q4*4 + r;
            float linv = 1.0f / l_sh[ql];
            #pragma unroll
            for (int j = 0; j < 4; ++j){
                int dl = wn*64 + j*16 + ln;
                obase[(long long)ql*512 + dl] = blend*acc[i][j][r]*linv + ib*vm[j];
            }
        }
    }
}

// ---------------------------------------------------------------------------
extern "C" void kernel_launch(void* const* d_in, const int* in_sizes, int n_in,
                              void* d_out, int out_size, void* d_ws, size_t ws_size,
                              hipStream_t stream)
{
    (void)in_sizes; (void)n_in; (void)out_size; (void)ws_size;
    const float* Q  = (const float*)d_in[0];
    const float* K  = (const float*)d_in[1];
    const float* V  = (const float*)d_in[2];
    const float* ps = (const float*)d_in[3];
    const float* pb = (const float*)d_in[4];
    const float* w1 = (const float*)d_in[5];
    const float* b1 = (const float*)d_in[6];
    const float* w2 = (const float*)d_in[7];
    const float* b2 = (const float*)d_in[8];
    float* out = (float*)d_out;

    char* ws = (char*)d_ws;
    float* dragon_wq       = (float*)(ws);                                        // 8 KiB
    float* blend           = (float*)(ws + 8192);
    float* vmean           = (float*)(ws + 16384);                                // 16 KiB
    size_t off = 32768;
    unsigned short* Qb     = (unsigned short*)(ws + off);                         // 16 MiB
    unsigned short* Kb     = (unsigned short*)(ws + off + (size_t)16*1024*1024);  // 16 MiB
    unsigned short* Vt     = (unsigned short*)(ws + off + (size_t)32*1024*1024);  // 16 MiB
    unsigned short* Sp     = (unsigned short*)(ws + off + (size_t)48*1024*1024);  // 64 MiB

    hipMemsetAsync(vmean, 0, 4096*sizeof(float), stream);   // capture-legal memset node
    hipLaunchKernelGGL(k_conv,    dim3(3073),      dim3(256), 0, stream,
                       Q, K, V, ps, pb, w1, b1, w2, b2, Qb, Kb, Vt, vmean, dragon_wq, blend);
    hipLaunchKernelGGL(k_gemm_qk, dim3(8, 16, 8),  dim3(256), 0, stream,
                       Qb, Kb, dragon_wq, Sp);
    hipLaunchKernelGGL(k_gemm_pv, dim3(4, 16, 8),  dim3(256), 0, stream,
                       Sp, Vt, vmean, blend, out);
}

// Round 5
// 263.955 us; speedup vs baseline: 1.1040x; 1.1040x over previous
//
#include <hip/hip_runtime.h>
#include <cstdint>

#define DEV __device__ __forceinline__

typedef float f32x4 __attribute__((ext_vector_type(4)));
typedef short s16x8 __attribute__((ext_vector_type(8)));

DEV unsigned short f2bf(float f){
    unsigned u = __builtin_bit_cast(unsigned, f);
    u = u + 0x7fffu + ((u >> 16) & 1u);   // RNE
    return (unsigned short)(u >> 16);
}
DEV float bf2f(unsigned short h){
    unsigned u = ((unsigned)h) << 16;
    return __builtin_bit_cast(float, u);
}

typedef const void __attribute__((address_space(1)))* gcp;
typedef void __attribute__((address_space(3)))* lp;
DEV void gload_lds16(const void* g, void* l){
    // async global->LDS, 16B per lane; LDS dest = wave-uniform base + lane*16
    __builtin_amdgcn_global_load_lds((gcp)g, (lp)l, 16, 0, 0);
}

#define SCALE_QK 0.04419417382415922f   // 1/sqrt(512)

// ---------------------------------------------------------------------------
// Conv (grid 3073):
//   blocks 0..1023  : Q -> bf16, K -> bf16 (RAW: dragon weight factored out
//                     of the dot product, applied in gemm_qk epilogue)
//   blocks 1024..3071: V -> Vt (bf16 [b][d][s]) + vmean atomics
//   block 3072      : dragon pattern + blend (concurrent; consumed later)
// ---------------------------------------------------------------------------
__global__ __launch_bounds__(256) void k_conv(
    const float* __restrict__ Q, const float* __restrict__ K,
    const float* __restrict__ V,
    const float* __restrict__ scale, const float* __restrict__ bias,
    const float* __restrict__ w1, const float* __restrict__ b1,
    const float* __restrict__ w2, const float* __restrict__ b2,
    unsigned short* __restrict__ Qb, unsigned short* __restrict__ Kb,
    unsigned short* __restrict__ Vt, float* __restrict__ vmean,
    float* __restrict__ dragon_wq, float* __restrict__ blend_out)
{
    __shared__ float sh[8200];
    int tid = threadIdx.x;
    int bx  = blockIdx.x;

    if (bx < 1024){
        // ---- Q,K -> bf16 streaming ----
        const long long total4 = (long long)8*2048*512/4;   // 2097152
        long long stride = 1024LL*256;
        for (long long i = (long long)bx*256 + tid; i < total4; i += stride){
            long long base = i*4;
            const float4 q = *(const float4*)(Q + base);
            const float4 k = *(const float4*)(K + base);
            ushort4 qo, ko;
            qo.x = f2bf(q.x); qo.y = f2bf(q.y); qo.z = f2bf(q.z); qo.w = f2bf(q.w);
            ko.x = f2bf(k.x); ko.y = f2bf(k.y); ko.z = f2bf(k.z); ko.w = f2bf(k.w);
            *(ushort4*)(Qb + base) = qo;
            *(ushort4*)(Kb + base) = ko;
        }
        return;
    }

    if (bx < 3072){
        // ---- V transpose + vmean atomics ----
        int t = bx - 1024;                    // 0..2047 = 32 stile x 8 dtile x 8 b
        int stile = t & 31, dtile = (t >> 5) & 7, b = t >> 8;
        int s0 = stile*64, d0 = dtile*64;
        float (*tile)[66] = (float(*)[66])sh;  // 64x66 = 4224 floats
        float* red = sh + 4224;                // 256 floats
        int tx = tid & 63, ty = tid >> 6;
        const float* src = V + ((long long)b*2048 + s0)*512 + d0;
        #pragma unroll
        for (int r = 0; r < 16; ++r){
            int row = r*4 + ty;
            tile[row][tx] = src[(long long)row*512 + tx];
        }
        __syncthreads();
        unsigned short* dst = Vt + ((long long)b*512 + d0)*2048 + s0;
        #pragma unroll
        for (int r = 0; r < 16; ++r){
            int drow = r*4 + ty;
            dst[(long long)drow*2048 + tx] = f2bf(tile[tx][drow]);
        }
        int dcol = tid & 63, sp = tid >> 6;
        float s = 0.f;
        #pragma unroll
        for (int ii = 0; ii < 16; ++ii) s += tile[sp*16 + ii][dcol];
        red[sp*64 + dcol] = s;
        __syncthreads();
        if (sp == 0){
            float tot = red[dcol] + red[64+dcol] + red[128+dcol] + red[192+dcol];
            atomicAdd(&vmean[b*512 + d0 + dcol], tot * (1.0f/2048.0f));
        }
        return;
    }

    // ---- dragon pattern + blend (1 block) ----
    // pattern[11] length 4095 = 2*2048-1 -> np.interp picks element 2i.
    float* A    = sh;             // 4095
    float* Bb   = sh + 4095;      // 4095
    float* red8 = sh + 8190;      // 8
    int lane = tid & 63, w = tid >> 6;
    if (tid == 0) A[0] = 0.5f;
    __syncthreads();
    float lo = 0.f, rden = 1.f;   // patterns[0] used raw (no normalize)
    int len = 1;
    const float third = 1.0f/3.0f;
    for (int it = 1; it < 12; ++it){
        int n = len, nl = 2*n + 1;
        // expand with carried normalization of A
        for (int i = tid; i < nl; i += 256){
            float v;
            if (i < n)       v = (A[i] - lo) * rden;
            else if (i == n) v = 0.5f;
            else             v = 1.0f - (A[2*n - i] - lo) * rden;
            Bb[i] = v;
        }
        __syncthreads();
        // conv [1/3,1/3,1/3] zero-pad 'same'; fused local min/max
        float mn = 3.4e38f, mx = -3.4e38f;
        for (int i = tid; i < nl; i += 256){
            float s = Bb[i];
            if (i > 0)    s += Bb[i-1];
            if (i < nl-1) s += Bb[i+1];
            s *= third;
            A[i] = s;
            mn = fminf(mn, s); mx = fmaxf(mx, s);
        }
        #pragma unroll
        for (int off = 32; off > 0; off >>= 1){
            mn = fminf(mn, __shfl_xor(mn, off, 64));
            mx = fmaxf(mx, __shfl_xor(mx, off, 64));
        }
        if (lane == 0){ red8[w] = mn; red8[4 + w] = mx; }
        __syncthreads();
        mn = fminf(fminf(red8[0], red8[1]), fminf(red8[2], red8[3]));
        mx = fmaxf(fmaxf(red8[4], red8[5]), fmaxf(red8[6], red8[7]));
        lo = mn; rden = 1.0f / (mx - mn + 1e-8f);
        len = nl;
        __syncthreads();
    }
    // dragon_wq[s] = softplus(normpat[2s]*scale[11]+bias[11]) * 1/sqrt(512)
    float sc = scale[11], bi = bias[11];
    for (int i = tid; i < 2048; i += 256){
        float x = (A[2*i] - lo) * rden * sc + bi;
        dragon_wq[i] = (fmaxf(x, 0.f) + log1pf(__expf(-fabsf(x)))) * SCALE_QK;
    }
    if (tid < 64){
        float h = fmaxf(w1[11*64 + tid] + b1[tid], 0.f);
        float c = h * w2[tid];
        for (int off = 32; off > 0; off >>= 1) c += __shfl_xor(c, off, 64);
        if (tid == 0) blend_out[0] = 1.f/(1.f + __expf(-(c + b2[0])));
    }
}

// ---------------------------------------------------------------------------
// GEMM 1: Sp[b,q,k] = bf16( exp( (Qb . Kb^T) * wq[k] ) )   (wq = w/sqrt(512))
// 128x128 tile (the proven occupancy sweet spot: 88 VGPR, 32KB LDS), BK=64,
// 4 waves (2x2), 4x4 MFMA 16x16x32. XOR-swizzled LDS -> 0 bank conflicts.
// ---------------------------------------------------------------------------
__global__ __launch_bounds__(256) void k_gemm_qk(
    const unsigned short* __restrict__ Qb, const unsigned short* __restrict__ Kb,
    const float* __restrict__ dragon_wq, unsigned short* __restrict__ Sp)
{
    __shared__ unsigned short At[128*64];
    __shared__ unsigned short Bt[128*64];
    int tid = threadIdx.x;
    int lane = tid & 63, wave = tid >> 6;
    int wm = wave >> 1, wn = wave & 1;
    int ln = lane & 15, q4 = lane >> 4;
    int sx = ln & 7;
    int q0 = blockIdx.y*128, k0 = blockIdx.x*128, b = blockIdx.z;
    const unsigned short* Abase = Qb + ((long long)b*2048 + q0)*512;
    const unsigned short* Bbase = Kb + ((long long)b*2048 + k0)*512;

    f32x4 acc[4][4];
    #pragma unroll
    for (int i = 0; i < 4; ++i)
        #pragma unroll
        for (int j = 0; j < 4; ++j) acc[i][j] = (f32x4)0.0f;

    int cc = lane & 7, rg = lane >> 3;
    for (int kt = 0; kt < 8; ++kt){
        #pragma unroll
        for (int c = 0; c < 4; ++c){
            int chunk = wave*4 + c;                 // 16 x 1KB chunks per tile
            int row = chunk*8 + rg;
            int gc  = cc ^ (row & 7);               // swizzled source chunk
            gload_lds16(Abase + (long long)row*512 + kt*64 + gc*8, &At[chunk*512]);
            gload_lds16(Bbase + (long long)row*512 + kt*64 + gc*8, &Bt[chunk*512]);
        }
        __syncthreads();
        #pragma unroll
        for (int ks = 0; ks < 2; ++ks){
            int cs = ((ks*4 + q4) ^ sx) * 8;        // swizzled fragment chunk
            s16x8 af[4], bfr[4];
            #pragma unroll
            for (int i = 0; i < 4; ++i)
                af[i] = *(const s16x8*)&At[(wm*64 + i*16 + ln)*64 + cs];
            #pragma unroll
            for (int j = 0; j < 4; ++j)
                bfr[j] = *(const s16x8*)&Bt[(wn*64 + j*16 + ln)*64 + cs];
            #pragma unroll
            for (int i = 0; i < 4; ++i)
                #pragma unroll
                for (int j = 0; j < 4; ++j)
                    acc[i][j] = __builtin_amdgcn_mfma_f32_16x16x32_bf16(af[i], bfr[j], acc[i][j], 0, 0, 0);
        }
        __syncthreads();
    }
    float wq[4];
    #pragma unroll
    for (int j = 0; j < 4; ++j) wq[j] = dragon_wq[k0 + wn*64 + j*16 + ln];
    unsigned short* outp = Sp + (long long)b*2048*2048;
    #pragma unroll
    for (int i = 0; i < 4; ++i){
        #pragma unroll
        for (int j = 0; j < 4; ++j){
            #pragma unroll
            for (int r = 0; r < 4; ++r){
                int q = q0 + wm*64 + i*16 + q4*4 + r;   // C/D: row=(lane>>4)*4+reg
                int k = k0 + wn*64 + j*16 + ln;         //      col=lane&15
                outp[(long long)q*2048 + k] = f2bf(__expf(acc[i][j][r] * wq[j]));
            }
        }
    }
}

// ---------------------------------------------------------------------------
// GEMM 2: out[b,q,d] = blend * (Sp . V) / l[q] + (1-blend) * Vmean[d]
// l[q] = sum_k Sp[q,k] from the A-fragments (wn==0 waves only).
// Grid flattened to 512 with XCD-aware decode: the 4 d-tiles sharing one
// (q,b) pair's Sp rows get ids == same (mod 8) -> same XCD L2 -> Sp rows
// fetched ~once per pair instead of 4x across non-coherent L2s.
// ---------------------------------------------------------------------------
__global__ __launch_bounds__(256) void k_gemm_pv(
    const unsigned short* __restrict__ Sp, const unsigned short* __restrict__ Vt,
    const float* __restrict__ vmean, const float* __restrict__ blendp,
    float* __restrict__ out)
{
    __shared__ unsigned short At[128*64];
    __shared__ unsigned short Bt[128*64];
    __shared__ float l_sh[128];
    int tid = threadIdx.x;
    int lane = tid & 63, wave = tid >> 6;
    int wm = wave >> 1, wn = wave & 1;
    int ln = lane & 15, q4 = lane >> 4;
    int sx = ln & 7;

    // XCD-aware decode: g%8 = XCD (heuristic); 64 slots/XCD; 4 consecutive
    // slots = the 4 d-tiles of one (q,b) pair.
    int g    = blockIdx.x;             // 0..511
    int xcd  = g & 7, slot = g >> 3;   // slot 0..63
    int pair = xcd*16 + (slot >> 2);   // 0..127
    int dt   = slot & 3;
    int qt   = pair & 15, b = pair >> 4;
    int q0 = qt*128, d0 = dt*128;

    const unsigned short* Abase = Sp + (long long)b*2048*2048 + (long long)q0*2048;
    const unsigned short* Bbase = Vt + ((long long)b*512 + d0)*2048;

    f32x4 acc[4][4];
    #pragma unroll
    for (int i = 0; i < 4; ++i)
        #pragma unroll
        for (int j = 0; j < 4; ++j) acc[i][j] = (f32x4)0.0f;
    float lsum[4] = {0.f, 0.f, 0.f, 0.f};

    int cc = lane & 7, rg = lane >> 3;
    for (int kt = 0; kt < 32; ++kt){
        #pragma unroll
        for (int c = 0; c < 4; ++c){
            int chunk = wave*4 + c;
            int row = chunk*8 + rg;
            int gc  = cc ^ (row & 7);
            gload_lds16(Abase + (long long)row*2048 + kt*64 + gc*8, &At[chunk*512]);
            gload_lds16(Bbase + (long long)row*2048 + kt*64 + gc*8, &Bt[chunk*512]);
        }
        __syncthreads();
        #pragma unroll
        for (int ks = 0; ks < 2; ++ks){
            int cs = ((ks*4 + q4) ^ sx) * 8;
            s16x8 af[4], bfr[4];
            #pragma unroll
            for (int i = 0; i < 4; ++i)
                af[i] = *(const s16x8*)&At[(wm*64 + i*16 + ln)*64 + cs];
            #pragma unroll
            for (int j = 0; j < 4; ++j)
                bfr[j] = *(const s16x8*)&Bt[(wn*64 + j*16 + ln)*64 + cs];
            if (wn == 0){
                #pragma unroll
                for (int i = 0; i < 4; ++i){
                    float s = 0.f;
                    #pragma unroll
                    for (int jj = 0; jj < 8; ++jj) s += bf2f((unsigned short)af[i][jj]);
                    lsum[i] += s;
                }
            }
            #pragma unroll
            for (int i = 0; i < 4; ++i)
                #pragma unroll
                for (int j = 0; j < 4; ++j)
                    acc[i][j] = __builtin_amdgcn_mfma_f32_16x16x32_bf16(af[i], bfr[j], acc[i][j], 0, 0, 0);
        }
        __syncthreads();
    }
    if (wn == 0){
        #pragma unroll
        for (int i = 0; i < 4; ++i){
            float v = lsum[i];
            v += __shfl_xor(v, 16, 64);
            v += __shfl_xor(v, 32, 64);
            if (lane < 16) l_sh[wm*64 + i*16 + lane] = v;
        }
    }
    __syncthreads();

    float blend = blendp[0];
    float ib = 1.0f - blend;
    float* obase = out + ((long long)b*2048 + q0)*512 + d0;
    float vm[4];
    #pragma unroll
    for (int j = 0; j < 4; ++j) vm[j] = vmean[b*512 + d0 + wn*64 + j*16 + ln];
    #pragma unroll
    for (int i = 0; i < 4; ++i){
        #pragma unroll
        for (int r = 0; r < 4; ++r){
            int ql = wm*64 + i*16 + q4*4 + r;
            float linv = 1.0f / l_sh[ql];
            #pragma unroll
            for (int j = 0; j < 4; ++j){
                int dl = wn*64 + j*16 + ln;
                obase[(long long)ql*512 + dl] = blend*acc[i][j][r]*linv + ib*vm[j];
            }
        }
    }
}

// ---------------------------------------------------------------------------
extern "C" void kernel_launch(void* const* d_in, const int* in_sizes, int n_in,
                              void* d_out, int out_size, void* d_ws, size_t ws_size,
                              hipStream_t stream)
{
    (void)in_sizes; (void)n_in; (void)out_size; (void)ws_size;
    const float* Q  = (const float*)d_in[0];
    const float* K  = (const float*)d_in[1];
    const float* V  = (const float*)d_in[2];
    const float* ps = (const float*)d_in[3];
    const float* pb = (const float*)d_in[4];
    const float* w1 = (const float*)d_in[5];
    const float* b1 = (const float*)d_in[6];
    const float* w2 = (const float*)d_in[7];
    const float* b2 = (const float*)d_in[8];
    float* out = (float*)d_out;

    char* ws = (char*)d_ws;
    float* dragon_wq       = (float*)(ws);                                        // 8 KiB
    float* blend           = (float*)(ws + 8192);
    float* vmean           = (float*)(ws + 16384);                                // 16 KiB
    size_t off = 32768;
    unsigned short* Qb     = (unsigned short*)(ws + off);                         // 16 MiB
    unsigned short* Kb     = (unsigned short*)(ws + off + (size_t)16*1024*1024);  // 16 MiB
    unsigned short* Vt     = (unsigned short*)(ws + off + (size_t)32*1024*1024);  // 16 MiB
    unsigned short* Sp     = (unsigned short*)(ws + off + (size_t)48*1024*1024);  // 64 MiB

    hipMemsetAsync(vmean, 0, 4096*sizeof(float), stream);   // capture-legal memset node
    hipLaunchKernelGGL(k_conv,    dim3(3073),      dim3(256), 0, stream,
                       Q, K, V, ps, pb, w1, b1, w2, b2, Qb, Kb, Vt, vmean, dragon_wq, blend);
    hipLaunchKernelGGL(k_gemm_qk, dim3(16, 16, 8), dim3(256), 0, stream,
                       Qb, Kb, dragon_wq, Sp);
    hipLaunchKernelGGL(k_gemm_pv, dim3(512),       dim3(256), 0, stream,
                       Sp, Vt, vmean, blend, out);
}